// Round 5
// baseline (763.318 us; speedup 1.0000x reference)
//
#include <hip/hip_runtime.h>
#include <hip/hip_bf16.h>

typedef __bf16  bf16x8 __attribute__((ext_vector_type(8)));
typedef __bf16  bf16x4 __attribute__((ext_vector_type(4)));
typedef float   f32x4  __attribute__((ext_vector_type(4)));
typedef int     i32x4  __attribute__((ext_vector_type(4)));

#define M_DIM 2048
#define K_DIM 2048
#define V_DIM 50257
#define V_PAD 50432                 // 197 * 256
#define BM 256
#define BN 256
#define BK 64
#define NT (K_DIM / BK)             // 32
#define SLOT_E 8192                 // elements per half-slot: 256 rows x 32 k = 16 KB

__device__ __forceinline__ void gl_lds16(const __bf16* g, __bf16* l) {
    __builtin_amdgcn_global_load_lds(
        (const __attribute__((address_space(1))) void*)g,
        (__attribute__((address_space(3))) void*)l, 16, 0, 0);
}

// ---------- prepass 1: A f32 -> bf16 (2048x2048) ----------
__global__ __launch_bounds__(256)
void cvtA(const float* __restrict__ hs, __bf16* __restrict__ a) {
    int i = (blockIdx.x * 256 + threadIdx.x) * 8;
    f32x4 v0 = *(const f32x4*)(hs + i);
    f32x4 v1 = *(const f32x4*)(hs + i + 4);
    bf16x8 t;
#pragma unroll
    for (int j = 0; j < 4; ++j) { t[j] = (__bf16)v0[j]; t[4 + j] = (__bf16)v1[j]; }
    *(bf16x8*)(a + i) = t;
}

// ---------- prepass 2: W[k][v] int32 -> Wt[v][k] bf16, zero-padded to V_PAD ----------
__global__ __launch_bounds__(256)
void cvtW(const int* __restrict__ wq, __bf16* __restrict__ wt) {
    __shared__ __attribute__((aligned(16))) __bf16 tls[64][72];
    const int t  = threadIdx.x;
    const int v0 = blockIdx.x * 64;
    const int k0 = blockIdx.y * 64;
    const int vb = t & 15, kb = t >> 4;
    const bool edge = (v0 + 64 > V_DIM);

    __bf16 cv[4][4];
#pragma unroll
    for (int j = 0; j < 4; ++j) {
        const int* p = wq + (size_t)(k0 + kb * 4 + j) * V_DIM + v0 + vb * 4;
        if (!edge) {
            i32x4 w = *(const i32x4*)p;
#pragma unroll
            for (int i = 0; i < 4; ++i) cv[j][i] = (__bf16)(float)w[i];
        } else {
#pragma unroll
            for (int i = 0; i < 4; ++i) {
                int v = v0 + vb * 4 + i;
                cv[j][i] = (v < V_DIM) ? (__bf16)(float)p[i] : (__bf16)0.0f;
            }
        }
    }
#pragma unroll
    for (int i = 0; i < 4; ++i) {
        bf16x4 c = { cv[0][i], cv[1][i], cv[2][i], cv[3][i] };
        *(bf16x4*)(&tls[vb * 4 + i][kb * 4]) = c;
    }
    __syncthreads();
    const int v = t >> 2, ko = (t & 3) * 16;
    bf16x8 r0 = *(const bf16x8*)(&tls[v][ko]);
    bf16x8 r1 = *(const bf16x8*)(&tls[v][ko + 8]);
    __bf16* op = wt + (size_t)(v0 + v) * K_DIM + k0 + ko;
    *(bf16x8*)op = r0;
    *(bf16x8*)(op + 8) = r1;
}

// ---------- main GEMM: 256x256 tile, m201-faithful 8-phase (T1+T2+T3+T4+T5) ----------
// Per phase: {ds_reads; 1 half-slot stage; [lgkmcnt(8) if 12 reads]; s_barrier;
//             lgkmcnt(0); setprio(1); 16 MFMA; setprio(0); s_barrier}.
// vmcnt(6) ONCE per K-tile (ph4, after stage, before first barrier).
// Slot ledger: every half-slot overwrite is >=1 {lgkmcnt(0)+barrier} after its
// last read; every read's data is forced landed by a vmcnt >=3 phases after issue.
// Tail: clamped-address stages keep the vmcnt instruction count uniform.
__global__ __launch_bounds__(512, 1)
void lmhead_gemm_8ph(const __bf16* __restrict__ A, const __bf16* __restrict__ Bt,
                     const float* __restrict__ scale, const float* __restrict__ bias,
                     float* __restrict__ out)
{
    __shared__ __attribute__((aligned(16))) __bf16 sm[8 * SLOT_E];   // 128 KB

    const int tid  = threadIdx.x;
    const int lane = tid & 63;
    const int wv   = tid >> 6;       // 0..7
    const int wm   = wv >> 2;        // 0..1 -> 128 M rows
    const int wn   = wv & 3;         // 0..3 -> 64 N cols

    // bijective XCD-chunked swizzle: 1576 blocks = 8 * 197
    int bid  = blockIdx.x;
    int wgid = (bid & 7) * 197 + (bid >> 3);
    const int m0 = (wgid & 7) * BM;          // m fast-varying: 8 M-blocks share B-panel in L2
    const int n0 = (wgid >> 3) * BN;

    const int la = lane & 15, hi = lane >> 4;
    const int swz  = ((la >> 1) & 3) << 4;           // byte swizzle from row bits 1-2
    const int colo = ((hi * 16) ^ swz) >> 1;         // element col offset within 32-k half

    int offA[8], offB[4];
#pragma unroll
    for (int f = 0; f < 8; ++f) offA[f] = (wm * 128 + f * 16 + la) * 32 + colo;
#pragma unroll
    for (int n = 0; n < 4; ++n) offB[n] = (wn * 64 + n * 16 + la) * 32 + colo;

    // staging: lane l covers row (chunk*16 + l>>2), k-granule (l&3)^((l>>3)&3)
    const int ksl  = (((lane & 3) ^ ((lane >> 3) & 3))) * 8;   // element offset
    const int srow = lane >> 2;

    auto stageA = [&](int tt, int kk) {
        const int slot = (tt & 1) * 2 + kk;
        const int ta   = (tt < NT) ? tt : (NT - 1);   // clamp addr, keep issue count
#pragma unroll
        for (int r = 0; r < 2; ++r) {
            int chunk = wv + 8 * r;
            int row   = chunk * 16 + srow;
            gl_lds16(A + (size_t)(m0 + row) * K_DIM + ta * BK + kk * 32 + ksl,
                     sm + slot * SLOT_E + chunk * 512);
        }
    };
    auto stageB = [&](int tt, int kk) {
        const int slot = 4 + (tt & 1) * 2 + kk;
        const int ta   = (tt < NT) ? tt : (NT - 1);
#pragma unroll
        for (int r = 0; r < 2; ++r) {
            int chunk = wv + 8 * r;
            int row   = chunk * 16 + srow;
            gl_lds16(Bt + (size_t)(n0 + row) * K_DIM + ta * BK + kk * 32 + ksl,
                     sm + slot * SLOT_E + chunk * 512);
        }
    };

    f32x4 acc[8][4];
#pragma unroll
    for (int f = 0; f < 8; ++f)
#pragma unroll
        for (int n = 0; n < 4; ++n) acc[f][n] = (f32x4)(0.0f);

    // ---- prologue: 7 halves; vmcnt(6) leaves newest 3 {A(1,0),B(1,0),B(1,1)}
    //      in flight; tile0's 4 halves forced landed ----
    stageA(0, 0); stageB(0, 0); stageA(0, 1); stageB(0, 1);
    stageA(1, 0); stageB(1, 0); stageB(1, 1);
    asm volatile("s_waitcnt vmcnt(6)" ::: "memory");
    __builtin_amdgcn_s_barrier();

#pragma unroll 1
    for (int t = 0; t < NT; ++t) {
        const __bf16* As0 = sm + ((t & 1) * 2 + 0) * SLOT_E;
        const __bf16* As1 = sm + ((t & 1) * 2 + 1) * SLOT_E;
        const __bf16* Bs0 = sm + (4 + (t & 1) * 2 + 0) * SLOT_E;
        const __bf16* Bs1 = sm + (4 + (t & 1) * 2 + 1) * SLOT_E;
        bf16x8 a[4], bk[4];

        // ================= ph1: kk=0, M-frags 0-3 (12 ds_reads) =================
#pragma unroll
        for (int f = 0; f < 4; ++f) a[f]  = *(const bf16x8*)(As0 + offA[f]);
#pragma unroll
        for (int n = 0; n < 4; ++n) bk[n] = *(const bf16x8*)(Bs0 + offB[n]);
        stageA(t + 1, 1);                        // slot freed at (t-1).ph4
        asm volatile("s_waitcnt lgkmcnt(8)" ::: "memory");   // pre-drain hint
        __builtin_amdgcn_s_barrier();
        asm volatile("s_waitcnt lgkmcnt(0)" ::: "memory");
        __builtin_amdgcn_s_setprio(1);
#pragma unroll
        for (int f = 0; f < 4; ++f)
#pragma unroll
            for (int n = 0; n < 4; ++n)
                acc[f][n] = __builtin_amdgcn_mfma_f32_16x16x32_bf16(a[f], bk[n], acc[f][n], 0, 0, 0);
        __builtin_amdgcn_s_setprio(0);
        __builtin_amdgcn_s_barrier();

        // ================= ph2: kk=0, M-frags 4-7 (4 ds_reads, B in regs) =================
#pragma unroll
        for (int f = 0; f < 4; ++f) a[f] = *(const bf16x8*)(As0 + offA[4 + f]);
        stageB(t + 2, 0);                        // slot freed at ph1 (lgkm0+barrier)
        __builtin_amdgcn_s_barrier();
        asm volatile("s_waitcnt lgkmcnt(0)" ::: "memory");
        __builtin_amdgcn_s_setprio(1);
#pragma unroll
        for (int f = 0; f < 4; ++f)
#pragma unroll
            for (int n = 0; n < 4; ++n)
                acc[4 + f][n] = __builtin_amdgcn_mfma_f32_16x16x32_bf16(a[f], bk[n], acc[4 + f][n], 0, 0, 0);
        __builtin_amdgcn_s_setprio(0);
        __builtin_amdgcn_s_barrier();

        // ================= ph3: kk=1, M-frags 0-3 (12 ds_reads) =================
#pragma unroll
        for (int f = 0; f < 4; ++f) a[f]  = *(const bf16x8*)(As1 + offA[f]);
#pragma unroll
        for (int n = 0; n < 4; ++n) bk[n] = *(const bf16x8*)(Bs1 + offB[n]);
        stageA(t + 2, 0);                        // slot freed at ph2
        asm volatile("s_waitcnt lgkmcnt(8)" ::: "memory");
        __builtin_amdgcn_s_barrier();
        asm volatile("s_waitcnt lgkmcnt(0)" ::: "memory");
        __builtin_amdgcn_s_setprio(1);
#pragma unroll
        for (int f = 0; f < 4; ++f)
#pragma unroll
            for (int n = 0; n < 4; ++n)
                acc[f][n] = __builtin_amdgcn_mfma_f32_16x16x32_bf16(a[f], bk[n], acc[f][n], 0, 0, 0);
        __builtin_amdgcn_s_setprio(0);
        __builtin_amdgcn_s_barrier();

        // ================= ph4: kk=1, M-frags 4-7 (4 ds_reads) + vmcnt(6) =================
#pragma unroll
        for (int f = 0; f < 4; ++f) a[f] = *(const bf16x8*)(As1 + offA[4 + f]);
        stageB(t + 2, 1);                        // slot freed at ph3
        asm volatile("s_waitcnt vmcnt(6)" ::: "memory");   // once per K-tile; covers all
        __builtin_amdgcn_s_barrier();                      // of tile t+1's reads
        asm volatile("s_waitcnt lgkmcnt(0)" ::: "memory");
        __builtin_amdgcn_s_setprio(1);
#pragma unroll
        for (int f = 0; f < 4; ++f)
#pragma unroll
            for (int n = 0; n < 4; ++n)
                acc[4 + f][n] = __builtin_amdgcn_mfma_f32_16x16x32_bf16(a[f], bk[n], acc[4 + f][n], 0, 0, 0);
        __builtin_amdgcn_s_setprio(0);
        __builtin_amdgcn_s_barrier();
    }

    asm volatile("s_waitcnt vmcnt(0)" ::: "memory");   // drain clamped tail loads

    // ---- epilogue: D row = hi*4+r (m side), col = la (n side) ----
#pragma unroll
    for (int nf = 0; nf < 4; ++nf) {
        int n = n0 + wn * 64 + nf * 16 + la;
        bool ok = (n < V_DIM);
        int nc = ok ? n : 0;
        float sc = scale[nc];
        float bi = bias[nc];
#pragma unroll
        for (int f = 0; f < 8; ++f) {
            int m = m0 + wm * 128 + f * 16 + hi * 4;
            float* op = out + (size_t)m * V_DIM + n;
#pragma unroll
            for (int r = 0; r < 4; ++r)
                if (ok) op[(size_t)r * V_DIM] = acc[f][nf][r] * sc + bi;
        }
    }
}

// ================= fallback (R0 kernel, used only if ws too small) =================
__global__ __launch_bounds__(256, 2)
void lmhead_gemm_fb(const float* __restrict__ hs, const int* __restrict__ wq,
                    const float* __restrict__ scale, const float* __restrict__ bias,
                    float* __restrict__ out)
{
    __shared__ __attribute__((aligned(16))) __bf16 smem[2 * 2 * 128 * 64];
    const int tid  = threadIdx.x;
    const int lane = tid & 63;
    const int wv   = tid >> 6;
    const int wm   = wv >> 1, wn = wv & 1;
    const int m0   = blockIdx.x * 128;
    const int n0   = blockIdx.y * 128;
    const bool edge = (n0 + 128 > V_DIM);
    const int ngB = tid >> 3, kgB = tid & 7;

    float a_reg[4][8];
    int   b_reg[8][4];
    f32x4 acc[4][4];
#pragma unroll
    for (int i = 0; i < 4; ++i)
#pragma unroll
        for (int j = 0; j < 4; ++j) acc[i][j] = (f32x4)(0.0f);

    auto load_tile = [&](int kt) {
#pragma unroll
        for (int g = 0; g < 4; ++g) {
            int c = tid + 256 * g;
            int row = c >> 3, kg = c & 7;
            const float* p = hs + (size_t)(m0 + row) * K_DIM + (size_t)kt * 64 + kg * 8;
            f32x4 v0 = *(const f32x4*)p;
            f32x4 v1 = *(const f32x4*)(p + 4);
#pragma unroll
            for (int j = 0; j < 4; ++j) { a_reg[g][j] = v0[j]; a_reg[g][4 + j] = v1[j]; }
        }
        const int kbase = kt * 64 + kgB * 8;
        if (!edge) {
            const int* p = wq + (size_t)kbase * V_DIM + n0 + ngB * 4;
#pragma unroll
            for (int j = 0; j < 8; ++j) {
                i32x4 v = *(const i32x4*)(p + (size_t)j * V_DIM);
#pragma unroll
                for (int i = 0; i < 4; ++i) b_reg[j][i] = v[i];
            }
        } else {
#pragma unroll
            for (int j = 0; j < 8; ++j)
#pragma unroll
                for (int i = 0; i < 4; ++i) {
                    int n = n0 + ngB * 4 + i;
                    b_reg[j][i] = (n < V_DIM) ? wq[(size_t)(kbase + j) * V_DIM + n] : 0;
                }
        }
    };
    auto store_tile = [&](int buf) {
        __bf16* As = smem + buf * (2 * 128 * 64);
        __bf16* Bs = As + 128 * 64;
#pragma unroll
        for (int g = 0; g < 4; ++g) {
            int c = tid + 256 * g;
            int row = c >> 3, kg = c & 7;
            bf16x8 t;
#pragma unroll
            for (int j = 0; j < 8; ++j) t[j] = (__bf16)a_reg[g][j];
            *(bf16x8*)(As + row * 64 + ((kg * 8) ^ ((row & 7) << 3))) = t;
        }
#pragma unroll
        for (int i = 0; i < 4; ++i) {
            int row = ngB * 4 + i;
            bf16x8 t;
#pragma unroll
            for (int j = 0; j < 8; ++j) t[j] = (__bf16)(float)b_reg[j][i];
            *(bf16x8*)(Bs + row * 64 + ((kgB * 8) ^ ((row & 7) << 3))) = t;
        }
    };
    auto compute = [&](int buf) {
        const __bf16* As = smem + buf * (2 * 128 * 64);
        const __bf16* Bs = As + 128 * 64;
        const int hi = lane >> 4, la = lane & 15;
#pragma unroll
        for (int kk = 0; kk < 2; ++kk) {
            bf16x8 af[4], bfr[4];
#pragma unroll
            for (int f = 0; f < 4; ++f) {
                int row = wm * 64 + f * 16 + la;
                af[f] = *(const bf16x8*)(As + row * 64 + ((kk * 32 + hi * 8) ^ ((row & 7) << 3)));
            }
#pragma unroll
            for (int f = 0; f < 4; ++f) {
                int row = wn * 64 + f * 16 + la;
                bfr[f] = *(const bf16x8*)(Bs + row * 64 + ((kk * 32 + hi * 8) ^ ((row & 7) << 3)));
            }
#pragma unroll
            for (int fm = 0; fm < 4; ++fm)
#pragma unroll
                for (int fn = 0; fn < 4; ++fn)
                    acc[fm][fn] = __builtin_amdgcn_mfma_f32_16x16x32_bf16(
                        af[fm], bfr[fn], acc[fm][fn], 0, 0, 0);
        }
    };

    load_tile(0); store_tile(0); __syncthreads();
    int cur = 0;
#pragma unroll 1
    for (int kt = 0; kt < NT - 1; ++kt) {
        load_tile(kt + 1);
        compute(cur);
        store_tile(cur ^ 1);
        __syncthreads();
        cur ^= 1;
    }
    compute(cur);

    const int hi = lane >> 4, la = lane & 15;
#pragma unroll
    for (int fn = 0; fn < 4; ++fn) {
        int n = n0 + wn * 64 + fn * 16 + la;
        bool ok = (n < V_DIM);
        int nc = ok ? n : 0;
        float sc = scale[nc];
        float bi = bias[nc];
#pragma unroll
        for (int fm = 0; fm < 4; ++fm) {
            int m = m0 + wm * 64 + fm * 16 + hi * 4;
            float* op = out + (size_t)m * V_DIM + n;
#pragma unroll
            for (int r = 0; r < 4; ++r)
                if (ok) op[(size_t)r * V_DIM] = acc[fm][fn][r] * sc + bi;
        }
    }
}

extern "C" void kernel_launch(void* const* d_in, const int* in_sizes, int n_in,
                              void* d_out, int out_size, void* d_ws, size_t ws_size,
                              hipStream_t stream) {
    const float* hs    = (const float*)d_in[0];
    const int*   wq    = (const int*)d_in[1];
    const float* scale = (const float*)d_in[2];
    const float* bias  = (const float*)d_in[3];
    float*       out   = (float*)d_out;

    const size_t needA = (size_t)M_DIM * K_DIM * 2;               // 8 MB
    const size_t needW = (size_t)V_PAD * K_DIM * 2;               // ~206.6 MB
    if (ws_size >= needA + needW) {
        __bf16* Abf = (__bf16*)d_ws;
        __bf16* Wt  = (__bf16*)((char*)d_ws + needA);
        cvtA<<<dim3(M_DIM * K_DIM / (256 * 8)), dim3(256), 0, stream>>>(hs, Abf);
        cvtW<<<dim3(V_PAD / 64, K_DIM / 64), dim3(256), 0, stream>>>(wq, Wt);
        lmhead_gemm_8ph<<<dim3(8 * (V_PAD / BN)), dim3(512), 0, stream>>>(
            Abf, Wt, scale, bias, out);
    } else {
        lmhead_gemm_fb<<<dim3(M_DIM / 128, (V_DIM + 127) / 128), dim3(256), 0, stream>>>(
            hs, wq, scale, bias, out);
    }
}

// Round 6
// 645.547 us; speedup vs baseline: 1.1824x; 1.1824x over previous
//
#include <hip/hip_runtime.h>
#include <hip/hip_bf16.h>

typedef __bf16  bf16x8 __attribute__((ext_vector_type(8)));
typedef __bf16  bf16x4 __attribute__((ext_vector_type(4)));
typedef float   f32x4  __attribute__((ext_vector_type(4)));
typedef int     i32x4  __attribute__((ext_vector_type(4)));

#define M_DIM 2048
#define K_DIM 2048
#define V_DIM 50257
#define V_PAD 50304                 // 393 * 128
#define BM 128
#define BN 128
#define BK 64
#define NT (K_DIM / BK)

__device__ __forceinline__ void gl_lds16(const __bf16* g, __bf16* l) {
    __builtin_amdgcn_global_load_lds(
        (const __attribute__((address_space(1))) void*)g,
        (__attribute__((address_space(3))) void*)l, 16, 0, 0);
}

// ---------- prepass 1: A f32 -> bf16 (2048x2048) ----------
__global__ __launch_bounds__(256)
void cvtA(const float* __restrict__ hs, __bf16* __restrict__ a) {
    int i = (blockIdx.x * 256 + threadIdx.x) * 8;
    f32x4 v0 = *(const f32x4*)(hs + i);
    f32x4 v1 = *(const f32x4*)(hs + i + 4);
    bf16x8 t;
#pragma unroll
    for (int j = 0; j < 4; ++j) { t[j] = (__bf16)v0[j]; t[4 + j] = (__bf16)v1[j]; }
    *(bf16x8*)(a + i) = t;
}

// ---------- prepass 2: W[k][v] int32 -> Wt[v][k] bf16, zero-padded to V_PAD ----------
__global__ __launch_bounds__(256)
void cvtW(const int* __restrict__ wq, __bf16* __restrict__ wt) {
    __shared__ __attribute__((aligned(16))) __bf16 tls[64][72];
    const int t  = threadIdx.x;
    const int v0 = blockIdx.x * 64;
    const int k0 = blockIdx.y * 64;
    const int vb = t & 15, kb = t >> 4;
    const bool edge = (v0 + 64 > V_DIM);

    __bf16 cv[4][4];
#pragma unroll
    for (int j = 0; j < 4; ++j) {
        const int* p = wq + (size_t)(k0 + kb * 4 + j) * V_DIM + v0 + vb * 4;
        if (!edge) {
            i32x4 w = *(const i32x4*)p;
#pragma unroll
            for (int i = 0; i < 4; ++i) cv[j][i] = (__bf16)(float)w[i];
        } else {
#pragma unroll
            for (int i = 0; i < 4; ++i) {
                int v = v0 + vb * 4 + i;
                cv[j][i] = (v < V_DIM) ? (__bf16)(float)p[i] : (__bf16)0.0f;
            }
        }
    }
#pragma unroll
    for (int i = 0; i < 4; ++i) {
        bf16x4 c = { cv[0][i], cv[1][i], cv[2][i], cv[3][i] };
        *(bf16x4*)(&tls[vb * 4 + i][kb * 4]) = c;
    }
    __syncthreads();
    const int v = t >> 2, ko = (t & 3) * 16;
    bf16x8 r0 = *(const bf16x8*)(&tls[v][ko]);
    bf16x8 r1 = *(const bf16x8*)(&tls[v][ko + 8]);
    __bf16* op = wt + (size_t)(v0 + v) * K_DIM + k0 + ko;
    *(bf16x8*)op = r0;
    *(bf16x8*)(op + 8) = r1;
}

// ---------- main GEMM: m97 structure + T2 swizzle + 4 blocks/CU ----------
// 128x128 tile, BK=64, single LDS buffer (32 KB), 2 barriers/K-step,
// global_load_lds width-16 staging with PRE-SWIZZLED global source:
//   LDS[row][cb] = logical[row][cb ^ ((row&7)<<4)]  (rule 21: linear dest,
//   inverse-swizzled source, swizzled ds_read) -> conflict-free fragment reads.
__global__ __launch_bounds__(256, 4)
void lmhead_gemm_bf16(const __bf16* __restrict__ A, const __bf16* __restrict__ Bt,
                      const float* __restrict__ scale, const float* __restrict__ bias,
                      float* __restrict__ out)
{
    __shared__ __attribute__((aligned(16))) __bf16 As[BM * BK];   // 16 KB
    __shared__ __attribute__((aligned(16))) __bf16 Bs[BN * BK];   // 16 KB

    const int tid  = threadIdx.x;
    const int lane = tid & 63;
    const int wv   = tid >> 6;
    const int wm   = wv >> 1, wn = wv & 1;

    // bijective XCD-chunked swizzle: 6288 blocks, 6288/8 = 786 exact.
    int bid  = blockIdx.x;
    int wgid = (bid & 7) * 786 + (bid >> 3);
    const int m0 = (wgid & 15) * BM;          // M fast-varying within an XCD chunk
    const int n0 = (wgid >> 4) * BN;

    const int hi = lane >> 4, la = lane & 15;
    // swizzled ds_read col offsets (elements), kk = 0/1; row&7 == la&7
    const int colo0 = (0 * 32 + hi * 8) ^ ((la & 7) * 8);
    const int colo1 = (1 * 32 + hi * 8) ^ ((la & 7) * 8);

    f32x4 acc[4][4];
#pragma unroll
    for (int i = 0; i < 4; ++i)
#pragma unroll
        for (int j = 0; j < 4; ++j) acc[i][j] = (f32x4)(0.0f);

    // staging lane decomposition: row-in-granule = lane>>3, chunk = lane&7
    const int l8 = lane >> 3, l7 = lane & 7;
    const int csrc = (l7 ^ l8) * 8;          // pre-swizzled source chunk (elements)

#pragma unroll 1
    for (int kt = 0; kt < NT; ++kt) {
        // ---- stage: 16 KB each of A,B via 8 gload_lds(1KB) per wave ----
#pragma unroll
        for (int i = 0; i < 4; ++i) {
            int seg = wv * 4 + i;                                // 0..15, wave-uniform
            int row = seg * 8 + l8;
            gl_lds16(A  + (size_t)(m0 + row) * K_DIM + kt * BK + csrc, As + seg * 512);
            gl_lds16(Bt + (size_t)(n0 + row) * K_DIM + kt * BK + csrc, Bs + seg * 512);
        }
        __syncthreads();   // drains vmcnt(0): tiles resident

        // ---- compute: 16 ds_read_b128 (conflict-free) + 32 MFMA per wave ----
#pragma unroll
        for (int kk = 0; kk < 2; ++kk) {
            const int colo = kk ? colo1 : colo0;
            bf16x8 af[4], bf[4];
#pragma unroll
            for (int f = 0; f < 4; ++f)
                af[f] = *(const bf16x8*)(As + (wm * 64 + f * 16 + la) * BK + colo);
#pragma unroll
            for (int f = 0; f < 4; ++f)
                bf[f] = *(const bf16x8*)(Bs + (wn * 64 + f * 16 + la) * BK + colo);
#pragma unroll
            for (int fm = 0; fm < 4; ++fm)
#pragma unroll
                for (int fn = 0; fn < 4; ++fn)
                    acc[fm][fn] = __builtin_amdgcn_mfma_f32_16x16x32_bf16(
                        af[fm], bf[fn], acc[fm][fn], 0, 0, 0);
        }
        __syncthreads();   // compute done before next overwrite
    }

    // ---- epilogue: fn INNER so the 4x64B segments of each 128-row merge in L2 ----
    float sc[4], bi[4];
    bool  okn[4];
#pragma unroll
    for (int fn = 0; fn < 4; ++fn) {
        int n = n0 + wn * 64 + fn * 16 + la;
        okn[fn] = (n < V_DIM);
        int nc = okn[fn] ? n : 0;
        sc[fn] = scale[nc];
        bi[fn] = bias[nc];
    }
#pragma unroll
    for (int f = 0; f < 4; ++f) {
#pragma unroll
        for (int r = 0; r < 4; ++r) {
            int m = m0 + wm * 64 + f * 16 + hi * 4 + r;
            float* op = out + (size_t)m * V_DIM + n0 + wn * 64 + la;
#pragma unroll
            for (int fn = 0; fn < 4; ++fn)
                if (okn[fn]) op[fn * 16] = acc[f][fn][r] * sc[fn] + bi[fn];
        }
    }
}

// ================= fallback (R0 kernel, used only if ws too small) =================
__global__ __launch_bounds__(256, 2)
void lmhead_gemm_fb(const float* __restrict__ hs, const int* __restrict__ wq,
                    const float* __restrict__ scale, const float* __restrict__ bias,
                    float* __restrict__ out)
{
    __shared__ __attribute__((aligned(16))) __bf16 smem[2 * 2 * 128 * 64];
    const int tid  = threadIdx.x;
    const int lane = tid & 63;
    const int wv   = tid >> 6;
    const int wm   = wv >> 1, wn = wv & 1;
    const int m0   = blockIdx.x * 128;
    const int n0   = blockIdx.y * 128;
    const bool edge = (n0 + 128 > V_DIM);
    const int ngB = tid >> 3, kgB = tid & 7;

    float a_reg[4][8];
    int   b_reg[8][4];
    f32x4 acc[4][4];
#pragma unroll
    for (int i = 0; i < 4; ++i)
#pragma unroll
        for (int j = 0; j < 4; ++j) acc[i][j] = (f32x4)(0.0f);

    auto load_tile = [&](int kt) {
#pragma unroll
        for (int g = 0; g < 4; ++g) {
            int c = tid + 256 * g;
            int row = c >> 3, kg = c & 7;
            const float* p = hs + (size_t)(m0 + row) * K_DIM + (size_t)kt * 64 + kg * 8;
            f32x4 v0 = *(const f32x4*)p;
            f32x4 v1 = *(const f32x4*)(p + 4);
#pragma unroll
            for (int j = 0; j < 4; ++j) { a_reg[g][j] = v0[j]; a_reg[g][4 + j] = v1[j]; }
        }
        const int kbase = kt * 64 + kgB * 8;
        if (!edge) {
            const int* p = wq + (size_t)kbase * V_DIM + n0 + ngB * 4;
#pragma unroll
            for (int j = 0; j < 8; ++j) {
                i32x4 v = *(const i32x4*)(p + (size_t)j * V_DIM);
#pragma unroll
                for (int i = 0; i < 4; ++i) b_reg[j][i] = v[i];
            }
        } else {
#pragma unroll
            for (int j = 0; j < 8; ++j)
#pragma unroll
                for (int i = 0; i < 4; ++i) {
                    int n = n0 + ngB * 4 + i;
                    b_reg[j][i] = (n < V_DIM) ? wq[(size_t)(kbase + j) * V_DIM + n] : 0;
                }
        }
    };
    auto store_tile = [&](int buf) {
        __bf16* As = smem + buf * (2 * 128 * 64);
        __bf16* Bs = As + 128 * 64;
#pragma unroll
        for (int g = 0; g < 4; ++g) {
            int c = tid + 256 * g;
            int row = c >> 3, kg = c & 7;
            bf16x8 t;
#pragma unroll
            for (int j = 0; j < 8; ++j) t[j] = (__bf16)a_reg[g][j];
            *(bf16x8*)(As + row * 64 + ((kg * 8) ^ ((row & 7) << 3))) = t;
        }
#pragma unroll
        for (int i = 0; i < 4; ++i) {
            int row = ngB * 4 + i;
            bf16x8 t;
#pragma unroll
            for (int j = 0; j < 8; ++j) t[j] = (__bf16)(float)b_reg[j][i];
            *(bf16x8*)(Bs + row * 64 + ((kgB * 8) ^ ((row & 7) << 3))) = t;
        }
    };
    auto compute = [&](int buf) {
        const __bf16* As = smem + buf * (2 * 128 * 64);
        const __bf16* Bs = As + 128 * 64;
        const int hi = lane >> 4, la = lane & 15;
#pragma unroll
        for (int kk = 0; kk < 2; ++kk) {
            bf16x8 af[4], bfr[4];
#pragma unroll
            for (int f = 0; f < 4; ++f) {
                int row = wm * 64 + f * 16 + la;
                af[f] = *(const bf16x8*)(As + row * 64 + ((kk * 32 + hi * 8) ^ ((row & 7) << 3)));
            }
#pragma unroll
            for (int f = 0; f < 4; ++f) {
                int row = wn * 64 + f * 16 + la;
                bfr[f] = *(const bf16x8*)(Bs + row * 64 + ((kk * 32 + hi * 8) ^ ((row & 7) << 3)));
            }
#pragma unroll
            for (int fm = 0; fm < 4; ++fm)
#pragma unroll
                for (int fn = 0; fn < 4; ++fn)
                    acc[fm][fn] = __builtin_amdgcn_mfma_f32_16x16x32_bf16(
                        af[fm], bfr[fn], acc[fm][fn], 0, 0, 0);
        }
    };

    load_tile(0); store_tile(0); __syncthreads();
    int cur = 0;
#pragma unroll 1
    for (int kt = 0; kt < NT - 1; ++kt) {
        load_tile(kt + 1);
        compute(cur);
        store_tile(cur ^ 1);
        __syncthreads();
        cur ^= 1;
    }
    compute(cur);

    const int hi = lane >> 4, la = lane & 15;
#pragma unroll
    for (int fn = 0; fn < 4; ++fn) {
        int n = n0 + wn * 64 + fn * 16 + la;
        bool ok = (n < V_DIM);
        int nc = ok ? n : 0;
        float sc = scale[nc];
        float bi = bias[nc];
#pragma unroll
        for (int fm = 0; fm < 4; ++fm) {
            int m = m0 + wm * 64 + fm * 16 + hi * 4;
            float* op = out + (size_t)m * V_DIM + n;
#pragma unroll
            for (int r = 0; r < 4; ++r)
                if (ok) op[(size_t)r * V_DIM] = acc[fm][fn][r] * sc + bi;
        }
    }
}

extern "C" void kernel_launch(void* const* d_in, const int* in_sizes, int n_in,
                              void* d_out, int out_size, void* d_ws, size_t ws_size,
                              hipStream_t stream) {
    const float* hs    = (const float*)d_in[0];
    const int*   wq    = (const int*)d_in[1];
    const float* scale = (const float*)d_in[2];
    const float* bias  = (const float*)d_in[3];
    float*       out   = (float*)d_out;

    const size_t needA = (size_t)M_DIM * K_DIM * 2;               // 8 MB
    const size_t needW = (size_t)V_PAD * K_DIM * 2;               // ~206 MB
    if (ws_size >= needA + needW) {
        __bf16* Abf = (__bf16*)d_ws;
        __bf16* Wt  = (__bf16*)((char*)d_ws + needA);
        cvtA<<<dim3(M_DIM * K_DIM / (256 * 8)), dim3(256), 0, stream>>>(hs, Abf);
        cvtW<<<dim3(V_PAD / 64, K_DIM / 64), dim3(256), 0, stream>>>(wq, Wt);
        lmhead_gemm_bf16<<<dim3(16 * (V_PAD / BN)), dim3(256), 0, stream>>>(
            Abf, Wt, scale, bias, out);
    } else {
        lmhead_gemm_fb<<<dim3(M_DIM / 128, (V_DIM + 127) / 128), dim3(256), 0, stream>>>(
            hs, wq, scale, bias, out);
    }
}

// Round 7
// 469.901 us; speedup vs baseline: 1.6244x; 1.3738x over previous
//
#include <hip/hip_runtime.h>
#include <hip/hip_bf16.h>

typedef char  i8x4  __attribute__((ext_vector_type(4)));
typedef char  i8x8  __attribute__((ext_vector_type(8)));
typedef float f32x4 __attribute__((ext_vector_type(4)));
typedef int   i32x4 __attribute__((ext_vector_type(4)));
typedef __bf16 bf16x8 __attribute__((ext_vector_type(8)));

#define M_DIM 2048
#define K_DIM 2048
#define V_DIM 50257
#define V_PAD 50304                 // 393 * 128
#define BM 128
#define BN 128
#define BK8 128                     // i8 K-tile (128 B per LDS row)
#define NT8 (K_DIM / BK8)           // 16

__device__ __forceinline__ void gl_lds16(const void* g, void* l) {
    __builtin_amdgcn_global_load_lds(
        (const __attribute__((address_space(1))) void*)g,
        (__attribute__((address_space(3))) void*)l, 16, 0, 0);
}

// ---------- prepass 1: A f32 -> int8 per-row symmetric quant ----------
__global__ __launch_bounds__(256)
void cvtA_i8(const float* __restrict__ hs, char* __restrict__ a8,
             float* __restrict__ rowsc) {
    __shared__ float red[4];
    const int row = blockIdx.x;
    const int t   = threadIdx.x;
    const float* rp = hs + (size_t)row * K_DIM + t * 8;
    f32x4 v0 = *(const f32x4*)rp;
    f32x4 v1 = *(const f32x4*)(rp + 4);
    float amax = 0.0f;
#pragma unroll
    for (int j = 0; j < 4; ++j)
        amax = fmaxf(amax, fmaxf(fabsf(v0[j]), fabsf(v1[j])));
#pragma unroll
    for (int off = 32; off; off >>= 1)
        amax = fmaxf(amax, __shfl_xor(amax, off, 64));
    if ((t & 63) == 0) red[t >> 6] = amax;
    __syncthreads();
    amax = fmaxf(fmaxf(red[0], red[1]), fmaxf(red[2], red[3]));
    amax = fmaxf(amax, 1e-30f);
    const float s = 127.0f / amax;
    i8x8 o;
#pragma unroll
    for (int j = 0; j < 4; ++j) {
        o[j]     = (char)__float2int_rn(v0[j] * s);
        o[4 + j] = (char)__float2int_rn(v1[j] * s);
    }
    *(i8x8*)(a8 + (size_t)row * K_DIM + t * 8) = o;
    if (t == 0) rowsc[row] = amax / 127.0f;
}

// ---------- prepass 2: W[k][v] int32 -> Wt8[v][k] int8, zero-padded to V_PAD ----------
__global__ __launch_bounds__(256)
void cvtW_i8(const int* __restrict__ wq, char* __restrict__ wt8) {
    __shared__ __attribute__((aligned(16))) char tls[64][80];
    const int t  = threadIdx.x;
    const int v0 = blockIdx.x * 64;
    const int k0 = blockIdx.y * 64;
    const int vb = t & 15, kb = t >> 4;
    const bool edge = (v0 + 64 > V_DIM);

    char cv[4][4];                     // [j=k][i=v]
#pragma unroll
    for (int j = 0; j < 4; ++j) {
        const int* p = wq + (size_t)(k0 + kb * 4 + j) * V_DIM + v0 + vb * 4;
        if (!edge) {
            i32x4 w = *(const i32x4*)p;
#pragma unroll
            for (int i = 0; i < 4; ++i) cv[j][i] = (char)w[i];
        } else {
#pragma unroll
            for (int i = 0; i < 4; ++i) {
                int v = v0 + vb * 4 + i;
                cv[j][i] = (v < V_DIM) ? (char)p[i] : (char)0;
            }
        }
    }
#pragma unroll
    for (int i = 0; i < 4; ++i) {
        i8x4 c = { cv[0][i], cv[1][i], cv[2][i], cv[3][i] };
        *(i8x4*)(&tls[vb * 4 + i][kb * 4]) = c;
    }
    __syncthreads();
    const int v = t >> 2, ko = (t & 3) * 16;
    i8x4 r0 = *(const i8x4*)(&tls[v][ko]);
    i8x4 r1 = *(const i8x4*)(&tls[v][ko + 4]);
    i8x4 r2 = *(const i8x4*)(&tls[v][ko + 8]);
    i8x4 r3 = *(const i8x4*)(&tls[v][ko + 12]);
    char* op = wt8 + (size_t)(v0 + v) * K_DIM + k0 + ko;
    *(i8x4*)(op)      = r0;
    *(i8x4*)(op + 4)  = r1;
    *(i8x4*)(op + 8)  = r2;
    *(i8x4*)(op + 12) = r3;
}

// ---------- main GEMM: int8 MFMA, m97 structure + T2 swizzle + 4 blocks/CU ----------
// 128x128 tile, BK=128 i8 (NT=16), single LDS buffer (32 KB), 2 barriers/K-step.
// LDS[row][cb] = logical[row][cb ^ ((row&7)*16)] via pre-swizzled gload source;
// ds_read applies the same XOR -> 2-way (free) bank access.
// acc is EXACT i32; epilogue: out = f32(acc) * (rowsc[m]*scale[n]) + bias[n].
__global__ __launch_bounds__(256, 4)
void lmhead_gemm_i8(const char* __restrict__ A8, const float* __restrict__ rowsc,
                    const char* __restrict__ Bt8,
                    const float* __restrict__ scale, const float* __restrict__ bias,
                    float* __restrict__ out)
{
    __shared__ __attribute__((aligned(16))) char As[BM * BK8];   // 16 KB
    __shared__ __attribute__((aligned(16))) char Bs[BN * BK8];   // 16 KB

    const int tid  = threadIdx.x;
    const int lane = tid & 63;
    const int wv   = tid >> 6;
    const int wm   = wv >> 1, wn = wv & 1;

    // bijective XCD-chunked swizzle: 6288 blocks, 6288/8 = 786 exact.
    int bid  = blockIdx.x;
    int wgid = (bid & 7) * 786 + (bid >> 3);
    const int m0 = (wgid & 15) * BM;          // M fast-varying within an XCD chunk
    const int n0 = (wgid >> 4) * BN;

    const int hi = lane >> 4, la = lane & 15;
    // swizzled ds_read byte offsets for kk=0/1 (frag = 16 i8 at k = kk*64 + hi*16)
    const int colo0 = (0 * 64 + hi * 16) ^ ((la & 7) << 4);
    const int colo1 = (1 * 64 + hi * 16) ^ ((la & 7) << 4);

    i32x4 acc[4][4];
#pragma unroll
    for (int i = 0; i < 4; ++i)
#pragma unroll
        for (int j = 0; j < 4; ++j) acc[i][j] = (i32x4)(0);

    // staging: lane = (l8 = row-in-granule, l7 = chunk); pre-swizzled source chunk
    const int l8 = lane >> 3, l7 = lane & 7;
    const int csrc = (l7 ^ l8) * 16;          // bytes within the 128-B row

#pragma unroll 1
    for (int kt = 0; kt < NT8; ++kt) {
        // ---- stage: 16 KB each of A,B via 4+4 gload_lds(1KB) per wave ----
#pragma unroll
        for (int i = 0; i < 4; ++i) {
            int seg = wv * 4 + i;                                // 0..15, wave-uniform
            int row = seg * 8 + l8;
            gl_lds16(A8  + (size_t)(m0 + row) * K_DIM + kt * BK8 + csrc, As + seg * 1024);
            gl_lds16(Bt8 + (size_t)(n0 + row) * K_DIM + kt * BK8 + csrc, Bs + seg * 1024);
        }
        __syncthreads();   // drains vmcnt(0): tiles resident

        // ---- compute: 16 ds_read_b128 (conflict-free) + 32 MFMA(16x16x64 i8) ----
#pragma unroll
        for (int kk = 0; kk < 2; ++kk) {
            const int colo = kk ? colo1 : colo0;
            i32x4 af[4], bf[4];
#pragma unroll
            for (int f = 0; f < 4; ++f)
                af[f] = *(const i32x4*)(As + (wm * 64 + f * 16 + la) * BK8 + colo);
#pragma unroll
            for (int f = 0; f < 4; ++f)
                bf[f] = *(const i32x4*)(Bs + (wn * 64 + f * 16 + la) * BK8 + colo);
#pragma unroll
            for (int fm = 0; fm < 4; ++fm)
#pragma unroll
                for (int fn = 0; fn < 4; ++fn)
                    acc[fm][fn] = __builtin_amdgcn_mfma_i32_16x16x64_i8(
                        af[fm], bf[fn], acc[fm][fn], 0, 0, 0);
        }
        __syncthreads();   // compute done before next overwrite
    }

    // ---- epilogue: fn INNER so 4x64B segments of each row merge in L2 ----
    float sc[4], bi[4];
    bool  okn[4];
#pragma unroll
    for (int fn = 0; fn < 4; ++fn) {
        int n = n0 + wn * 64 + fn * 16 + la;
        okn[fn] = (n < V_DIM);
        int nc = okn[fn] ? n : 0;
        sc[fn] = scale[nc];
        bi[fn] = bias[nc];
    }
#pragma unroll
    for (int f = 0; f < 4; ++f) {
#pragma unroll
        for (int r = 0; r < 4; ++r) {
            int m = m0 + wm * 64 + f * 16 + hi * 4 + r;
            float sa = rowsc[m];
            float* op = out + (size_t)m * V_DIM + n0 + wn * 64 + la;
#pragma unroll
            for (int fn = 0; fn < 4; ++fn)
                if (okn[fn]) op[fn * 16] = (float)acc[f][fn][r] * (sa * sc[fn]) + bi[fn];
        }
    }
}

// ================= fallback (R0 kernel, used only if ws too small) =================
__global__ __launch_bounds__(256, 2)
void lmhead_gemm_fb(const float* __restrict__ hs, const int* __restrict__ wq,
                    const float* __restrict__ scale, const float* __restrict__ bias,
                    float* __restrict__ out)
{
    __shared__ __attribute__((aligned(16))) __bf16 smem[2 * 2 * 128 * 64];
    const int tid  = threadIdx.x;
    const int lane = tid & 63;
    const int wv   = tid >> 6;
    const int wm   = wv >> 1, wn = wv & 1;
    const int m0   = blockIdx.x * 128;
    const int n0   = blockIdx.y * 128;
    const bool edge = (n0 + 128 > V_DIM);
    const int ngB = tid >> 3, kgB = tid & 7;

    float a_reg[4][8];
    int   b_reg[8][4];
    f32x4 acc[4][4];
#pragma unroll
    for (int i = 0; i < 4; ++i)
#pragma unroll
        for (int j = 0; j < 4; ++j) acc[i][j] = (f32x4)(0.0f);

    auto load_tile = [&](int kt) {
#pragma unroll
        for (int g = 0; g < 4; ++g) {
            int c = tid + 256 * g;
            int row = c >> 3, kg = c & 7;
            const float* p = hs + (size_t)(m0 + row) * K_DIM + (size_t)kt * 64 + kg * 8;
            f32x4 v0 = *(const f32x4*)p;
            f32x4 v1 = *(const f32x4*)(p + 4);
#pragma unroll
            for (int j = 0; j < 4; ++j) { a_reg[g][j] = v0[j]; a_reg[g][4 + j] = v1[j]; }
        }
        const int kbase = kt * 64 + kgB * 8;
        if (!edge) {
            const int* p = wq + (size_t)kbase * V_DIM + n0 + ngB * 4;
#pragma unroll
            for (int j = 0; j < 8; ++j) {
                i32x4 v = *(const i32x4*)(p + (size_t)j * V_DIM);
#pragma unroll
                for (int i = 0; i < 4; ++i) b_reg[j][i] = v[i];
            }
        } else {
#pragma unroll
            for (int j = 0; j < 8; ++j)
#pragma unroll
                for (int i = 0; i < 4; ++i) {
                    int n = n0 + ngB * 4 + i;
                    b_reg[j][i] = (n < V_DIM) ? wq[(size_t)(kbase + j) * V_DIM + n] : 0;
                }
        }
    };
    auto store_tile = [&](int buf) {
        __bf16* As = smem + buf * (2 * 128 * 64);
        __bf16* Bs = As + 128 * 64;
#pragma unroll
        for (int g = 0; g < 4; ++g) {
            int c = tid + 256 * g;
            int row = c >> 3, kg = c & 7;
            bf16x8 t;
#pragma unroll
            for (int j = 0; j < 8; ++j) t[j] = (__bf16)a_reg[g][j];
            *(bf16x8*)(As + row * 64 + ((kg * 8) ^ ((row & 7) << 3))) = t;
        }
#pragma unroll
        for (int i = 0; i < 4; ++i) {
            int row = ngB * 4 + i;
            bf16x8 t;
#pragma unroll
            for (int j = 0; j < 8; ++j) t[j] = (__bf16)(float)b_reg[j][i];
            *(bf16x8*)(Bs + row * 64 + ((kgB * 8) ^ ((row & 7) << 3))) = t;
        }
    };
    auto compute = [&](int buf) {
        const __bf16* As = smem + buf * (2 * 128 * 64);
        const __bf16* Bs = As + 128 * 64;
        const int hi = lane >> 4, la = lane & 15;
#pragma unroll
        for (int kk = 0; kk < 2; ++kk) {
            bf16x8 af[4], bfr[4];
#pragma unroll
            for (int f = 0; f < 4; ++f) {
                int row = wm * 64 + f * 16 + la;
                af[f] = *(const bf16x8*)(As + row * 64 + ((kk * 32 + hi * 8) ^ ((row & 7) << 3)));
            }
#pragma unroll
            for (int f = 0; f < 4; ++f) {
                int row = wn * 64 + f * 16 + la;
                bfr[f] = *(const bf16x8*)(Bs + row * 64 + ((kk * 32 + hi * 8) ^ ((row & 7) << 3)));
            }
#pragma unroll
            for (int fm = 0; fm < 4; ++fm)
#pragma unroll
                for (int fn = 0; fn < 4; ++fn)
                    acc[fm][fn] = __builtin_amdgcn_mfma_f32_16x16x32_bf16(
                        af[fm], bfr[fn], acc[fm][fn], 0, 0, 0);
        }
    };

    load_tile(0); store_tile(0); __syncthreads();
    int cur = 0;
#pragma unroll 1
    for (int kt = 0; kt < (K_DIM / 64) - 1; ++kt) {
        load_tile(kt + 1);
        compute(cur);
        store_tile(cur ^ 1);
        __syncthreads();
        cur ^= 1;
    }
    compute(cur);

    const int hi = lane >> 4, la = lane & 15;
#pragma unroll
    for (int fn = 0; fn < 4; ++fn) {
        int n = n0 + wn * 64 + fn * 16 + la;
        bool ok = (n < V_DIM);
        int nc = ok ? n : 0;
        float sc = scale[nc];
        float bi = bias[nc];
#pragma unroll
        for (int fm = 0; fm < 4; ++fm) {
            int m = m0 + wm * 64 + fm * 16 + hi * 4;
            float* op = out + (size_t)m * V_DIM + n;
#pragma unroll
            for (int r = 0; r < 4; ++r)
                if (ok) op[(size_t)r * V_DIM] = acc[fm][fn][r] * sc + bi;
        }
    }
}

extern "C" void kernel_launch(void* const* d_in, const int* in_sizes, int n_in,
                              void* d_out, int out_size, void* d_ws, size_t ws_size,
                              hipStream_t stream) {
    const float* hs    = (const float*)d_in[0];
    const int*   wq    = (const int*)d_in[1];
    const float* scale = (const float*)d_in[2];
    const float* bias  = (const float*)d_in[3];
    float*       out   = (float*)d_out;

    // ws layout: a8 [0, 4MB) | rowsc [4MB, +8KB) | Wt8 [8MB, +103MB)
    const size_t offRS = (size_t)M_DIM * K_DIM;            // 4 MB
    const size_t offW  = offRS + (4u << 20);               // 8 MB
    const size_t need  = offW + (size_t)V_PAD * K_DIM;     // ~111 MB
    if (ws_size >= need) {
        char*  a8    = (char*)d_ws;
        float* rowsc = (float*)((char*)d_ws + offRS);
        char*  wt8   = (char*)d_ws + offW;
        cvtA_i8<<<dim3(M_DIM), dim3(256), 0, stream>>>(hs, a8, rowsc);
        cvtW_i8<<<dim3(V_PAD / 64, K_DIM / 64), dim3(256), 0, stream>>>(wq, wt8);
        lmhead_gemm_i8<<<dim3(16 * (V_PAD / BN)), dim3(256), 0, stream>>>(
            a8, rowsc, wt8, scale, bias, out);
    } else {
        lmhead_gemm_fb<<<dim3(M_DIM / 128, (V_DIM + 127) / 128), dim3(256), 0, stream>>>(
            hs, wq, scale, bias, out);
    }
}